// Round 6
// baseline (106.644 us; speedup 1.0000x reference)
//
#include <hip/hip_runtime.h>
#include <math.h>

#define BIG_NEG -1.0e9f

typedef float f4 __attribute__((ext_vector_type(4)));

// Problem constants (fixed by setup_inputs)
constexpr int B  = 4;
constexpr int N1 = 511;
constexpr int C1 = 31;
constexpr int K  = 32;
constexpr int N  = N1 + 1;        // 512
constexpr int C  = C1 + 1;        // 32

// Workspace layout (float offsets)
constexpr int WS_TRANS = 0;                    // [32][32]
constexpr int WS_INIT  = 1024;                 // [32]
constexpr int WS_LEN   = 1056;                 // [32][32]  (K x C)
constexpr int WS_P     = 2080;                 // [64][64]  precision matrix
constexpr int WS_W     = 6176;                 // [64][32]  wT[dd][c]
constexpr int WS_BIAS  = 8224;                 // [32]
constexpr int WS_EMIS  = 8256;                 // [B][N][C] = 65536

// ---------------------------------------------------------------------------
// Fused prep: single-barrier Gauss-Jordan (pivot-column pipelining +
// active-column masking) + small tables + wT + bias.
// ---------------------------------------------------------------------------
__global__ __launch_bounds__(512) void k_prep(const float* __restrict__ tl,
                                              const float* __restrict__ il,
                                              const float* __restrict__ plr,
                                              const float* __restrict__ cov,
                                              const float* __restrict__ means,
                                              float* __restrict__ ws) {
    __shared__ float M[64][132];   // [cov | I], row stride 132 (16B aligned)
    __shared__ float fc[2][64];    // double-buffered pivot column
    __shared__ float piv[64];
    __shared__ float rpiv_s[64];
    __shared__ float mu[C1][64];
    __shared__ float s_logdet;

    const int tid = threadIdx.x;
    const int ii = tid >> 3;       // row 0..63
    const int cg = tid & 7;        // owns float4 chunks {cg, cg+8, cg+16, cg+24}

    f4* Mrow = (f4*)&M[ii][0];

    // ---- load [cov | I] ----
    {
        Mrow[cg]     = *(const f4*)&cov[ii * 64 + 4 * cg];
        Mrow[cg + 8] = *(const f4*)&cov[ii * 64 + 4 * (cg + 8)];
        const int r0 = 4 * cg, r1 = 4 * (cg + 8);
        f4 e1 = {(ii == r0) ? 1.f : 0.f, (ii == r0 + 1) ? 1.f : 0.f,
                 (ii == r0 + 2) ? 1.f : 0.f, (ii == r0 + 3) ? 1.f : 0.f};
        f4 e2 = {(ii == r1) ? 1.f : 0.f, (ii == r1 + 1) ? 1.f : 0.f,
                 (ii == r1 + 2) ? 1.f : 0.f, (ii == r1 + 3) ? 1.f : 0.f};
        Mrow[cg + 16] = e1;
        Mrow[cg + 24] = e2;
    }
    if (cg == 0) fc[0][ii] = cov[ii * 64];  // pivot column 0
    for (int idx = tid; idx < C1 * 64; idx += 512)
        mu[idx >> 6][idx & 63] = means[idx];
    __syncthreads();

    // ---- Gauss-Jordan: ONE barrier per step ----
    for (int jj = 0; jj < 64; ++jj) {
        const int par = jj & 1;
        const float p = fc[par][jj];
        const float f = fc[par][ii] / p;
        if (tid == 0) piv[jj] = p;
        const f4* Mjj = (const f4*)&M[jj][0];
        const bool upd = (ii != jj);
#pragma unroll
        for (int h = 0; h < 4; ++h) {
            const int q = cg + 8 * h;
            const int k0 = 4 * q;
            // active cols at step jj: {jj..63} U {64..64+jj}
            const bool active = (k0 < 64) ? (k0 + 3 >= jj) : (k0 - 64 <= jj);
            if (!active) continue;
            f4 v = Mrow[q];
            if (upd) {
                v = v - f * Mjj[q];
                Mrow[q] = v;
            }
            // publish next pivot column (col jj+1) for next step
            if (jj < 63 && (unsigned)(jj + 1 - k0) < 4u) {
                const int d = jj + 1 - k0;
                fc[par ^ 1][ii] = (d == 0) ? v.x : (d == 1) ? v.y
                                 : (d == 2) ? v.z : v.w;
            }
        }
        __syncthreads();
    }

    // ---- logdet + reciprocal pivots ----
    if (tid == 0) {
        float s = 0.0f;
        for (int r = 0; r < 64; ++r) s += logf(piv[r]);
        s_logdet = s;
    }
    if (tid < 64) rpiv_s[tid] = 1.0f / piv[tid];
    __syncthreads();

    // ---- P = inv(cov) to global: P[ii][c] = M[ii][64+c] * rpiv[ii] ----
    {
        const float rp = rpiv_s[ii];
        f4 a = Mrow[16 + cg] * rp;
        f4 b = Mrow[24 + cg] * rp;
        *(f4*)&ws[WS_P + ii * 64 + 4 * cg] = a;
        *(f4*)&ws[WS_P + ii * 64 + 32 + 4 * cg] = b;
    }

    // ---- small tables ----
    for (int idx = tid; idx < 1024; idx += 512) {
        const int i = idx >> 5, j = idx & 31;
        ws[WS_TRANS + idx] = (i == C1) ? 0.0f : BIG_NEG;
        float lv;
        if (j < C1) {
            float lr = plr[j];
            lv = (float)i * lr - expf(lr) - lgammaf((float)i + 1.0f);
        } else {
            lv = (i == 1) ? 0.0f : BIG_NEG;
        }
        ws[WS_LEN + idx] = lv;
    }
    if (tid < B * C) {
        const int bb = tid >> 5, cc = tid & 31;
        ws[WS_EMIS + (bb * N + N1) * C + cc] = (cc == C1) ? 0.0f : BIG_NEG;
    }
    // trans columns: log_softmax over axis 0 with masked diagonal
    if (tid < C1) {
        const int jj = tid;
        float m = BIG_NEG;
        for (int r = 0; r < C1; ++r) {
            float v = (r == jj) ? BIG_NEG : tl[r * C1 + jj];
            m = fmaxf(m, v);
        }
        float s = 0.0f;
        for (int r = 0; r < C1; ++r) {
            float v = (r == jj) ? BIG_NEG : tl[r * C1 + jj];
            s += expf(v - m);
        }
        float lse = m + logf(s);
        for (int r = 0; r < C1; ++r) {
            float v = (r == jj) ? BIG_NEG : tl[r * C1 + jj];
            ws[WS_TRANS + r * 32 + jj] = v - lse;
        }
    }
    // init_a
    if (tid == 256) {
        float m = -1.0e30f;
        for (int cc = 0; cc < C1; ++cc) m = fmaxf(m, il[cc]);
        float s = 0.0f;
        for (int cc = 0; cc < C1; ++cc) s += expf(il[cc] - m);
        float lse = m + logf(s);
        for (int cc = 0; cc < C1; ++cc) ws[WS_INIT + cc] = il[cc] - lse;
        ws[WS_INIT + C1] = BIG_NEG;
    }

    // ---- wT[dd][c] = rpiv[dd] * (row_dd(Pscaled) . mu_c); bias via shfl ----
    {
        const int c = tid >> 4;    // 0..31
        const int l = tid & 15;
        if (c < C1) {
            float qacc = 0.0f;
#pragma unroll
            for (int h = 0; h < 4; ++h) {
                const int dd = l + 16 * h;
                float a = 0.0f;
                for (int e = 0; e < 64; ++e) a += M[dd][64 + e] * mu[c][e];
                a *= rpiv_s[dd];
                ws[WS_W + dd * 32 + c] = a;
                qacc += a * mu[c][dd];
            }
            for (int m2 = 8; m2 >= 1; m2 >>= 1) qacc += __shfl_xor(qacc, m2, 64);
            if (l == 0)
                ws[WS_BIAS + c] =
                    -0.5f * (64.0f * 1.8378770664093453f + s_logdet + qacc);
        }
    }
}

// ---------------------------------------------------------------------------
// Emission log-probs: emis[b,n,c] = bias_c + w_c.x - 0.5 * x^T P x
// 4 waves per block, one wave per (b,n).
// ---------------------------------------------------------------------------
__global__ __launch_bounds__(256) void k_emis(const float* __restrict__ feat,
                                              float* __restrict__ ws) {
    const int tid = threadIdx.x;
    const int w = tid >> 6, lane = tid & 63;
    const int flat = blockIdx.x * 4 + w;          // == b*N1 + n, 0..2043
    const int b = flat / N1, n = flat % N1;
    __shared__ float xs[4][64];

    const float x = feat[flat * 64 + lane];
    xs[w][lane] = x;
    __syncthreads();

    const float* __restrict__ P = ws + WS_P;
    float z = 0.0f;
    for (int dd = 0; dd < 64; ++dd) z += P[dd * 64 + lane] * xs[w][dd];

    float xz = x * z;
    for (int m = 32; m >= 1; m >>= 1) xz += __shfl_xor(xz, m);

    float val = BIG_NEG;
    if (lane < C1) {
        float s = ws[WS_BIAS + lane] - 0.5f * xz;
        const float* __restrict__ wT = ws + WS_W;
        for (int dd = 0; dd < 64; ++dd) s += wT[dd * 32 + lane] * xs[w][dd];
        val = s;
    }
    if (lane < C) ws[WS_EMIS + (b * N + n) * C + lane] = val;
}

// ---------------------------------------------------------------------------
// Main assembly (fused local window-scan): one block per (b,t); loads emis
// rows t..t+31 into LDS, per-column prefix scan, then 32 coalesced f4 stores
// per thread-row along k. No global cumsum array, no k_cumsum kernel.
// ---------------------------------------------------------------------------
__global__ __launch_bounds__(256) void k_main(const float* __restrict__ ws,
                                              float* __restrict__ out) {
    const int bid = blockIdx.x;
    const int b = bid / N1, t = bid % N1;
    const int tid = threadIdx.x;
    __shared__ float sh[32][32];

    // load emis rows t..t+31 (zero past row N-1)
    {
        const int row = tid >> 3;            // 0..31
        const int c4 = (tid & 7) << 2;       // 0,4,...,28
        f4 v = {0.f, 0.f, 0.f, 0.f};
        if (t + row < N)
            v = *(const f4*)&ws[WS_EMIS + (b * N + t + row) * C + c4];
        *(f4*)&sh[row][c4] = v;
    }
    __syncthreads();

    // inclusive prefix scan along rows, per column (serial by 32 lanes;
    // hidden by the other co-resident blocks' store traffic)
    if (tid < 32) {
        float acc = 0.0f;
#pragma unroll
        for (int i = 0; i < 32; ++i) {
            acc += sh[i][tid];
            sh[i][tid] = acc;
        }
    }

    const int cp = tid >> 3;
    const int c0 = (tid & 7) << 2;
    f4 pre = *(const f4*)&ws[WS_TRANS + cp * 32 + c0];
    if (t == 0) {
        f4 in4 = *(const f4*)&ws[WS_INIT + c0];
        pre = pre + in4;
    }
    const float emisN = (cp == C1) ? 0.0f : BIG_NEG;
    const int keos = N1 - t;  // matches k only when 1 <= keos <= 31
    const size_t obase = (size_t)bid * (K * C * C) + (size_t)(cp * 32 + c0);
    __syncthreads();

#pragma unroll 4
    for (int k = 0; k < K; ++k) {
        f4 len4 = *(const f4*)&ws[WS_LEN + k * 32 + c0];
        f4 w4 = {0.f, 0.f, 0.f, 0.f};
        if (k > 0) w4 = *(const f4*)&sh[k - 1][c0];
        f4 o = pre + len4 + w4;
        if (k == keos) o = o + emisN;
        __builtin_nontemporal_store(o, (f4*)&out[obase + (size_t)k * (C * C)]);
    }
}

// ---------------------------------------------------------------------------
extern "C" void kernel_launch(void* const* d_in, const int* in_sizes, int n_in,
                              void* d_out, int out_size, void* d_ws, size_t ws_size,
                              hipStream_t stream) {
    const float* feat = (const float*)d_in[0];
    const float* tl   = (const float*)d_in[1];
    const float* il   = (const float*)d_in[2];
    const float* plr  = (const float*)d_in[3];
    const float* gm   = (const float*)d_in[4];
    const float* gc   = (const float*)d_in[5];
    float* ws  = (float*)d_ws;
    float* out = (float*)d_out;

    hipLaunchKernelGGL(k_prep, dim3(1), dim3(512), 0, stream, tl, il, plr, gc, gm, ws);
    hipLaunchKernelGGL(k_emis, dim3(B * N1 / 4), dim3(256), 0, stream, feat, ws);
    hipLaunchKernelGGL(k_main, dim3(B * N1), dim3(256), 0, stream, ws, out);
}

// Round 7
// 98.656 us; speedup vs baseline: 1.0810x; 1.0810x over previous
//
#include <hip/hip_runtime.h>
#include <math.h>

#define BIG_NEG -1.0e9f

typedef float f4 __attribute__((ext_vector_type(4)));

// Problem constants (fixed by setup_inputs)
constexpr int B  = 4;
constexpr int N1 = 511;
constexpr int C1 = 31;
constexpr int K  = 32;
constexpr int N  = N1 + 1;        // 512
constexpr int C  = C1 + 1;        // 32

// Workspace layout (float offsets)
constexpr int WS_TRANS = 0;                    // [32][32]
constexpr int WS_INIT  = 1024;                 // [32]
constexpr int WS_LEN   = 1056;                 // [32][32]  (K x C)
constexpr int WS_P     = 2080;                 // [64][64]  precision matrix
constexpr int WS_W     = 6176;                 // [64][32]  wT[dd][c]
constexpr int WS_BIAS  = 8224;                 // [32]
constexpr int WS_EMIS  = 8256;                 // [B][N][C] = 65536

// ---------------------------------------------------------------------------
// Fused prep: single-barrier Gauss-Jordan (pivot-column pipelining +
// active-column masking) + small tables + wT + bias.
// ---------------------------------------------------------------------------
__global__ __launch_bounds__(512) void k_prep(const float* __restrict__ tl,
                                              const float* __restrict__ il,
                                              const float* __restrict__ plr,
                                              const float* __restrict__ cov,
                                              const float* __restrict__ means,
                                              float* __restrict__ ws) {
    __shared__ float M[64][132];   // [cov | I], row stride 132 (16B aligned)
    __shared__ float fc[2][64];    // double-buffered pivot column
    __shared__ float piv[64];
    __shared__ float rpiv_s[64];
    __shared__ float mu[C1][64];
    __shared__ float s_logdet;

    const int tid = threadIdx.x;
    const int ii = tid >> 3;       // row 0..63
    const int cg = tid & 7;        // owns float4 chunks {cg, cg+8, cg+16, cg+24}

    f4* Mrow = (f4*)&M[ii][0];

    // ---- small tables (independent of LDS; disjoint writers, no race) ----
    for (int idx = tid; idx < 1024; idx += 512) {
        const int i = idx >> 5, j = idx & 31;
        float lv;
        if (j < C1) {
            float lr = plr[j];
            lv = (float)i * lr - expf(lr) - lgammaf((float)i + 1.0f);
        } else {
            lv = (i == 1) ? 0.0f : BIG_NEG;
        }
        ws[WS_LEN + idx] = lv;
        // trans defaults: row C1 = 0; col C1 (rows<C1) = BIG_NEG.
        // (r<C1, j<C1) cells are written only by the softmax below.
        if (i == C1) ws[WS_TRANS + idx] = 0.0f;
        else if (j == C1) ws[WS_TRANS + idx] = BIG_NEG;
    }
    if (tid < B * C) {
        const int bb = tid >> 5, cc = tid & 31;
        ws[WS_EMIS + (bb * N + N1) * C + cc] = (cc == C1) ? 0.0f : BIG_NEG;
    }
    // trans columns: log_softmax over axis 0 with masked diagonal
    if (tid < C1) {
        const int jj = tid;
        float m = BIG_NEG;
        for (int r = 0; r < C1; ++r) {
            float v = (r == jj) ? BIG_NEG : tl[r * C1 + jj];
            m = fmaxf(m, v);
        }
        float s = 0.0f;
        for (int r = 0; r < C1; ++r) {
            float v = (r == jj) ? BIG_NEG : tl[r * C1 + jj];
            s += expf(v - m);
        }
        float lse = m + logf(s);
        for (int r = 0; r < C1; ++r) {
            float v = (r == jj) ? BIG_NEG : tl[r * C1 + jj];
            ws[WS_TRANS + r * 32 + jj] = v - lse;
        }
    }
    // init_a
    if (tid == 32) {
        float m = -1.0e30f;
        for (int cc = 0; cc < C1; ++cc) m = fmaxf(m, il[cc]);
        float s = 0.0f;
        for (int cc = 0; cc < C1; ++cc) s += expf(il[cc] - m);
        float lse = m + logf(s);
        for (int cc = 0; cc < C1; ++cc) ws[WS_INIT + cc] = il[cc] - lse;
        ws[WS_INIT + C1] = BIG_NEG;
    }

    // ---- load [cov | I] ----
    {
        Mrow[cg]     = *(const f4*)&cov[ii * 64 + 4 * cg];
        Mrow[cg + 8] = *(const f4*)&cov[ii * 64 + 4 * (cg + 8)];
        const int r0 = 4 * cg, r1 = 4 * (cg + 8);
        f4 e1 = {(ii == r0) ? 1.f : 0.f, (ii == r0 + 1) ? 1.f : 0.f,
                 (ii == r0 + 2) ? 1.f : 0.f, (ii == r0 + 3) ? 1.f : 0.f};
        f4 e2 = {(ii == r1) ? 1.f : 0.f, (ii == r1 + 1) ? 1.f : 0.f,
                 (ii == r1 + 2) ? 1.f : 0.f, (ii == r1 + 3) ? 1.f : 0.f};
        Mrow[cg + 16] = e1;
        Mrow[cg + 24] = e2;
    }
    if (cg == 0) fc[0][ii] = cov[ii * 64];  // pivot column 0
    for (int idx = tid; idx < C1 * 64; idx += 512)
        mu[idx >> 6][idx & 63] = means[idx];
    __syncthreads();

    // ---- Gauss-Jordan: ONE barrier per step ----
    for (int jj = 0; jj < 64; ++jj) {
        const int par = jj & 1;
        const float p = fc[par][jj];
        const float f = fc[par][ii] / p;
        if (tid == 0) piv[jj] = p;
        const f4* Mjj = (const f4*)&M[jj][0];
        const bool upd = (ii != jj);
#pragma unroll
        for (int h = 0; h < 4; ++h) {
            const int q = cg + 8 * h;
            const int k0 = 4 * q;
            // active cols at step jj: {jj..63} U {64..64+jj}
            const bool active = (k0 < 64) ? (k0 + 3 >= jj) : (k0 - 64 <= jj);
            if (!active) continue;
            f4 v = Mrow[q];
            if (upd) {
                v = v - f * Mjj[q];
                Mrow[q] = v;
            }
            // publish next pivot column (col jj+1) for next step
            if (jj < 63 && (unsigned)(jj + 1 - k0) < 4u) {
                const int d = jj + 1 - k0;
                fc[par ^ 1][ii] = (d == 0) ? v.x : (d == 1) ? v.y
                                 : (d == 2) ? v.z : v.w;
            }
        }
        __syncthreads();
    }

    // ---- logdet (parallel, wave0) + reciprocal pivots ----
    if (tid < 64) {
        float lp = logf(piv[tid]);
        rpiv_s[tid] = 1.0f / piv[tid];
        for (int m2 = 32; m2 >= 1; m2 >>= 1) lp += __shfl_xor(lp, m2, 64);
        if (tid == 0) s_logdet = lp;
    }
    __syncthreads();

    // ---- P = inv(cov) to global: P[ii][c] = M[ii][64+c] * rpiv[ii] ----
    {
        const float rp = rpiv_s[ii];
        f4 a = Mrow[16 + cg] * rp;
        f4 b = Mrow[24 + cg] * rp;
        *(f4*)&ws[WS_P + ii * 64 + 4 * cg] = a;
        *(f4*)&ws[WS_P + ii * 64 + 32 + 4 * cg] = b;
    }

    // ---- wT[dd][c] = rpiv[dd] * (row_dd(Pscaled) . mu_c); bias via shfl ----
    {
        const int c = tid >> 4;    // 0..31
        const int l = tid & 15;
        if (c < C1) {
            const f4* muc = (const f4*)&mu[c][0];
            float qacc = 0.0f;
#pragma unroll
            for (int h = 0; h < 4; ++h) {
                const int dd = l + 16 * h;
                const f4* Mr = (const f4*)&M[dd][64];
                f4 a4 = {0.f, 0.f, 0.f, 0.f};
#pragma unroll
                for (int e4 = 0; e4 < 16; ++e4) a4 += Mr[e4] * muc[e4];
                float a = (a4.x + a4.y) + (a4.z + a4.w);
                a *= rpiv_s[dd];
                ws[WS_W + dd * 32 + c] = a;
                qacc += a * mu[c][dd];
            }
            for (int m2 = 8; m2 >= 1; m2 >>= 1) qacc += __shfl_xor(qacc, m2, 64);
            if (l == 0)
                ws[WS_BIAS + c] =
                    -0.5f * (64.0f * 1.8378770664093453f + s_logdet + qacc);
        }
    }
}

// ---------------------------------------------------------------------------
// Emission log-probs: emis[b,n,c] = bias_c + w_c.x - 0.5 * x^T P x
// 4 waves per block, one wave per (b,n); LDS slice is wave-local (no barrier).
// ---------------------------------------------------------------------------
__global__ __launch_bounds__(256) void k_emis(const float* __restrict__ feat,
                                              float* __restrict__ ws) {
    const int tid = threadIdx.x;
    const int w = tid >> 6, lane = tid & 63;
    const int flat = blockIdx.x * 4 + w;          // == b*N1 + n, 0..2043
    const int b = flat / N1, n = flat % N1;
    __shared__ float xs[4][64];

    const float x = feat[flat * 64 + lane];
    xs[w][lane] = x;   // wave-local slice; lgkmcnt ordering suffices

    const float* __restrict__ P = ws + WS_P;
    float z = 0.0f;
    for (int dd = 0; dd < 64; ++dd) z += P[dd * 64 + lane] * xs[w][dd];

    float xz = x * z;
    for (int m = 32; m >= 1; m >>= 1) xz += __shfl_xor(xz, m);

    float val = BIG_NEG;
    if (lane < C1) {
        float s = ws[WS_BIAS + lane] - 0.5f * xz;
        const float* __restrict__ wT = ws + WS_W;
        for (int dd = 0; dd < 64; ++dd) s += wT[dd * 32 + lane] * xs[w][dd];
        val = s;
    }
    if (lane < C) ws[WS_EMIS + (b * N + n) * C + lane] = val;
}

// ---------------------------------------------------------------------------
// Main assembly (fused local window-scan): one block per (b,t); loads emis
// rows t..t+31 into LDS, parallel per-column prefix scan (depth 4+3), then
// 32 coalesced plain f4 stores per thread along k.
// ---------------------------------------------------------------------------
__global__ __launch_bounds__(256) void k_main(const float* __restrict__ ws,
                                              float* __restrict__ out) {
    const int bid = blockIdx.x;
    const int b = bid / N1, t = bid % N1;
    const int tid = threadIdx.x;
    __shared__ float sh[32][36];   // stride 36: 16B-aligned rows, spread banks

    // load emis rows t..t+31 (zero past row N-1)
    {
        const int row = tid >> 3;            // 0..31
        const int c4 = (tid & 7) << 2;       // 0,4,...,28
        f4 v = {0.f, 0.f, 0.f, 0.f};
        if (t + row < N)
            v = *(const f4*)&ws[WS_EMIS + (b * N + t + row) * C + c4];
        *(f4*)&sh[row][c4] = v;
    }
    __syncthreads();

    // parallel inclusive prefix scan along rows, per column:
    // 8 threads per column, 4 serial rows each, then shfl_up scan over groups.
    {
        const int sc = tid >> 3;   // column 0..31
        const int g  = tid & 7;    // row group 0..7 (within-wave for shfl)
        float p0 = sh[4 * g + 0][sc];
        float p1 = p0 + sh[4 * g + 1][sc];
        float p2 = p1 + sh[4 * g + 2][sc];
        float p3 = p2 + sh[4 * g + 3][sc];
        float sum = p3;
#pragma unroll
        for (int off = 1; off < 8; off <<= 1) {
            float nv = __shfl_up(sum, off, 8);
            if (g >= off) sum += nv;
        }
        const float excl = sum - p3;
        sh[4 * g + 0][sc] = p0 + excl;
        sh[4 * g + 1][sc] = p1 + excl;
        sh[4 * g + 2][sc] = p2 + excl;
        sh[4 * g + 3][sc] = p3 + excl;
    }

    const int cp = tid >> 3;
    const int c0 = (tid & 7) << 2;
    f4 pre = *(const f4*)&ws[WS_TRANS + cp * 32 + c0];
    if (t == 0) {
        f4 in4 = *(const f4*)&ws[WS_INIT + c0];
        pre = pre + in4;
    }
    const float emisN = (cp == C1) ? 0.0f : BIG_NEG;
    const int keos = N1 - t;  // matches k only when 1 <= keos <= 31
    const size_t obase = (size_t)bid * (K * C * C) + (size_t)(cp * 32 + c0);
    __syncthreads();

#pragma unroll 4
    for (int k = 0; k < K; ++k) {
        f4 len4 = *(const f4*)&ws[WS_LEN + k * 32 + c0];
        f4 w4 = {0.f, 0.f, 0.f, 0.f};
        if (k > 0) w4 = *(const f4*)&sh[k - 1][c0];
        f4 o = pre + len4 + w4;
        if (k == keos) o = o + emisN;
        *(f4*)&out[obase + (size_t)k * (C * C)] = o;
    }
}

// ---------------------------------------------------------------------------
extern "C" void kernel_launch(void* const* d_in, const int* in_sizes, int n_in,
                              void* d_out, int out_size, void* d_ws, size_t ws_size,
                              hipStream_t stream) {
    const float* feat = (const float*)d_in[0];
    const float* tl   = (const float*)d_in[1];
    const float* il   = (const float*)d_in[2];
    const float* plr  = (const float*)d_in[3];
    const float* gm   = (const float*)d_in[4];
    const float* gc   = (const float*)d_in[5];
    float* ws  = (float*)d_ws;
    float* out = (float*)d_out;

    hipLaunchKernelGGL(k_prep, dim3(1), dim3(512), 0, stream, tl, il, plr, gc, gm, ws);
    hipLaunchKernelGGL(k_emis, dim3(B * N1 / 4), dim3(256), 0, stream, feat, ws);
    hipLaunchKernelGGL(k_main, dim3(B * N1), dim3(256), 0, stream, ws, out);
}